// Round 7
// baseline (872.393 us; speedup 1.0000x reference)
//
#include <hip/hip_runtime.h>

// Problem constants (from reference)
#define NBATCH 256
#define LI 2
#define LH 150
#define LQ 10
#define HS 128
#define WSD 128
#define KIT 40
#define AOUT 5

// Plane layout: 130 rows x 132 cols of dwords, pixel (y,x) -> plane[(y+1)*LCOLS + (x+1)].
// Row 0 / row 129 = zero halos; dword col 0 = left halo; cols 129..131 = right
// zero pad. With x0 = 4*tx, a thread's 6-wide window = dwords x0..x0+5:
// b128@x0 (16B aligned) + b64@x0+4; b128 halves are the even pairs.
#define LCOLS 132
#define LROWS 130
#define PLANE (LROWS * LCOLS)      // 17160 dwords
#define LDS_DWORDS (2 * PLANE)     // 137,280 B

// Workspace (floats):
//  [0..18] w_eff
//  [64 ..) per-block r planes (PLANE each)
//  then    per-block rq5 planes: channels 2..6, layout [y][c5][x], no halo.
#define WSOFF_RPLANES 64
#define WSOFF_RQ5 (WSOFF_RPLANES + NBATCH * PLANE)
#define RQ5PLANE (HS * 5 * WSD)    // 81,920 floats per block
#define WS_NEED_LDSONLY 0
#define WS_NEED15 ((size_t)(WSOFF_RQ5 + (size_t)NBATCH * RQ5PLANE) * 4)  // ~101.5 MB

typedef float v2f __attribute__((ext_vector_type(2)));
#define SPLAT(K) ((v2f){(K), (K)})
#define FMA2(A, B, C) __builtin_elementwise_fma((A), (B), (C))

// ---- Prep: collapse the linear hidden layer.
__global__ void prep_weff(const float* __restrict__ h_w,
                          const float* __restrict__ h_b,
                          const float* __restrict__ r_w,
                          float* __restrict__ w_eff) {
  const int t = threadIdx.x;
  if (t < 18) {
    const int i = t / 9, k = t % 9;
    double s = 0.0;
    for (int h = 0; h < LH; ++h)
      s += (double)r_w[h] * (double)h_w[(h * LI + i) * 9 + k];
    w_eff[t] = (float)s;
  } else if (t == 18) {
    double s = 0.0;
    for (int h = 0; h < LH; ++h)
      s += (double)r_w[h] * (double)h_b[h];
    w_eff[18] = (float)s;
  }
}

// SROA RULE (rounds 1-4): local arrays only ever indexed by compile-time
// literals. VALU LAW (rounds 7-9): f32-issue-bound; only issue-count cuts
// move the needle.
// ROUND 10: full rq (168 MB fp32) in ws -> ~200 MB hot set thrashed L3
// (45% miss), 3.6 GB HBM, 1046 us.
// ROUND 11: aggressive restructure => compiler +44% VALU, 868 us.
// CODEGEN LAW: round-9 body is fragile — minimal deltas only.
// ROUND 12: rq-phase + ch0/ch1 register-rq, 39 iters => 600 us, VGPR 60.
// ROUND 13/14: ch2/ch3 register-rq spilled (VGPR pinned at 64); both
// waves_per_eu(4,4) and __launch_bounds__(1024,4) failed to unlock 128.
// VGPR WALL LAW: 64 VGPRs is a hard budget for 1024-thr blocks here.
// ROUND 15: ch2..6 rq -> ws fp32 (84 MB, L3-resident: hot set 101 MB vs
// r10's 200), loaded per row as b128; ch7..9 recomputed (unroll 3 exact);
// ch0/1 stay register-resident. Bitwise-identical math.

// ---------- shared macros ----------
#define LOAD_PROW(P, R, W)                                                   \
  {                                                                          \
    const float4 b_ = *reinterpret_cast<const float4*>((P) + (R) * LCOLS);   \
    const float2 c_ = *reinterpret_cast<const float2*>((P) + (R) * LCOLS + 4); \
    W[0] = (v2f){b_.x, b_.y};                                                \
    W[1] = (v2f){b_.z, b_.w};                                                \
    W[2] = (v2f){c_.x, c_.y};                                                \
  }

#define TAPROW(KY, WARR, K0, K1, K2)                                         \
    a0 = FMA2(SPLAT(K0), WARR[KY][0], a0);                                   \
    a1 = FMA2(SPLAT(K0), WARR[KY][1], a1);                                   \
    a0.x = __builtin_fmaf((K1), WARR[KY][0].y, a0.x);                        \
    a0.y = __builtin_fmaf((K1), WARR[KY][1].x, a0.y);                        \
    a1.x = __builtin_fmaf((K1), WARR[KY][1].y, a1.x);                        \
    a1.y = __builtin_fmaf((K1), WARR[KY][2].x, a1.y);                        \
    a0 = FMA2(SPLAT(K2), WARR[KY][1], a0);                                   \
    a1 = FMA2(SPLAT(K2), WARR[KY][2], a1);

#define WIN_SHIFT2(NEXTROW)                                                  \
  {                                                                          \
    _Pragma("unroll")                                                        \
    for (int j = 0; j < 3; ++j) {                                            \
      rw[0][j] = rw[1][j]; rw[1][j] = rw[2][j];                              \
      vw[0][j] = vw[1][j]; vw[1][j] = vw[2][j];                              \
    }                                                                        \
    LOAD_PROW(rp, (NEXTROW), rw[2])                                          \
    LOAD_PROW(vp, (NEXTROW), vw[2])                                          \
  }

#define R_ROW(DY)                                                            \
  {                                                                          \
    v2f a0 = SPLAT(beff);                                                    \
    v2f a1 = a0;                                                             \
    TAPROW(0, rw, w_eff[0], w_eff[1], w_eff[2])                              \
    TAPROW(1, rw, w_eff[3], w_eff[4], w_eff[5])                              \
    TAPROW(2, rw, w_eff[6], w_eff[7], w_eff[8])                              \
    TAPROW(0, vw, w_eff[9], w_eff[10], w_eff[11])                            \
    TAPROW(1, vw, w_eff[12], w_eff[13], w_eff[14])                           \
    TAPROW(2, vw, w_eff[15], w_eff[16], w_eff[17])                           \
    racc[DY][0] = a0; racc[DY][1] = a1;                                      \
  }

// ---------- mod-3 slot machinery (round-9 form) ----------
// r window slot, even pairs only (scalar kx=1 taps).
#define LOADR(SLOT, R)                                                       \
  {                                                                          \
    const float4 b_ = *reinterpret_cast<const float4*>(rp + (R) * LCOLS);    \
    const float2 c_ = *reinterpret_cast<const float2*>(rp + (R) * LCOLS + 4); \
    rP[SLOT][0] = (v2f){b_.x, b_.y};                                         \
    rP[SLOT][1] = (v2f){b_.z, b_.w};                                         \
    rP[SLOT][2] = (v2f){c_.x, c_.y};                                         \
  }

// v window slot: even pairs + odd pairs (built once, reused per channel).
#define LOADV(SLOT, R)                                                       \
  {                                                                          \
    const float4 b_ = *reinterpret_cast<const float4*>(vp + (R) * LCOLS);    \
    const float2 c_ = *reinterpret_cast<const float2*>(vp + (R) * LCOLS + 4); \
    vE[SLOT][0] = (v2f){b_.x, b_.y};                                         \
    vE[SLOT][1] = (v2f){b_.z, b_.w};                                         \
    vE[SLOT][2] = (v2f){c_.x, c_.y};                                         \
    vO[SLOT][0] = (v2f){b_.y, b_.z};                                         \
    vO[SLOT][1] = (v2f){b_.w, c_.x};                                         \
  }

// r tap-row, scalar kx=1: 8 issues.
#define TAP_R(SLOT, K0, K1, K2)                                              \
    a0 = FMA2(SPLAT(K0), rP[SLOT][0], a0);                                   \
    a1 = FMA2(SPLAT(K0), rP[SLOT][1], a1);                                   \
    a0.x = __builtin_fmaf((K1), rP[SLOT][0].y, a0.x);                        \
    a0.y = __builtin_fmaf((K1), rP[SLOT][1].x, a0.y);                        \
    a1.x = __builtin_fmaf((K1), rP[SLOT][1].y, a1.x);                        \
    a1.y = __builtin_fmaf((K1), rP[SLOT][2].x, a1.y);                        \
    a0 = FMA2(SPLAT(K2), rP[SLOT][1], a0);                                   \
    a1 = FMA2(SPLAT(K2), rP[SLOT][2], a1);

// v tap-row: all-pk, 6 issues.
#define TAP_V(SLOT, K0, K1, K2)                                              \
    a0 = FMA2(SPLAT(K0), vE[SLOT][0], a0);                                   \
    a1 = FMA2(SPLAT(K0), vE[SLOT][1], a1);                                   \
    a0 = FMA2(SPLAT(K1), vO[SLOT][0], a0);                                   \
    a1 = FMA2(SPLAT(K1), vO[SLOT][1], a1);                                   \
    a0 = FMA2(SPLAT(K2), vE[SLOT][1], a0);                                   \
    a1 = FMA2(SPLAT(K2), vE[SLOT][2], a1);

// Full channel (round-9 form): r-half (scalar kx=1) + v-half.
#define VI_CH3(QC, WC, SA, SB, SC, MERGE)                                    \
  {                                                                          \
    const float* qc = (QC);                                                  \
    const float* wc = (WC);                                                  \
    v2f a0 = SPLAT(qc[0]) * rP[SA][0];                                       \
    v2f a1 = SPLAT(qc[0]) * rP[SA][1];                                       \
    a0.x = __builtin_fmaf(qc[1], rP[SA][0].y, a0.x);                         \
    a0.y = __builtin_fmaf(qc[1], rP[SA][1].x, a0.y);                         \
    a1.x = __builtin_fmaf(qc[1], rP[SA][1].y, a1.x);                         \
    a1.y = __builtin_fmaf(qc[1], rP[SA][2].x, a1.y);                         \
    a0 = FMA2(SPLAT(qc[2]), rP[SA][1], a0);                                  \
    a1 = FMA2(SPLAT(qc[2]), rP[SA][2], a1);                                  \
    TAP_R(SB, qc[3], qc[4], qc[5])                                           \
    TAP_R(SC, qc[6], qc[7], qc[8])                                           \
    TAP_V(SA, wc[0], wc[1], wc[2])                                           \
    TAP_V(SB, wc[3], wc[4], wc[5])                                           \
    TAP_V(SC, wc[6], wc[7], wc[8])                                           \
    MERGE                                                                    \
  }

// ---------- one-time rq-phase machinery ----------
#define RQ_CH3(QC, SA, SB, SC, MERGE)                                        \
  {                                                                          \
    const float* qc = (QC);                                                  \
    v2f a0 = SPLAT(qc[0]) * rP[SA][0];                                       \
    v2f a1 = SPLAT(qc[0]) * rP[SA][1];                                       \
    a0.x = __builtin_fmaf(qc[1], rP[SA][0].y, a0.x);                         \
    a0.y = __builtin_fmaf(qc[1], rP[SA][1].x, a0.y);                         \
    a1.x = __builtin_fmaf(qc[1], rP[SA][1].y, a1.x);                         \
    a1.y = __builtin_fmaf(qc[1], rP[SA][2].x, a1.y);                         \
    a0 = FMA2(SPLAT(qc[2]), rP[SA][1], a0);                                  \
    a1 = FMA2(SPLAT(qc[2]), rP[SA][2], a1);                                  \
    TAP_R(SB, qc[3], qc[4], qc[5])                                           \
    TAP_R(SC, qc[6], qc[7], qc[8])                                           \
    MERGE                                                                    \
  }

#define RQ_MX                                                                \
    m0 = __builtin_elementwise_max(m0, a0);                                  \
    m1 = __builtin_elementwise_max(m1, a1);

#define RQ_ST5(C5)                                                           \
    *reinterpret_cast<float4*>(sr + (C5) * WSD) =                            \
        make_float4(a0.x, a0.y, a1.x, a1.y);

// One rq output row: ch0/ch1 -> regs; ch2..6 -> ws; all 10 -> max -> v0 row.
#define RQ_OUT15(DY, SA, SB, SC)                                             \
  {                                                                          \
    float* sr = rq5_t + (DY) * (5 * WSD);                                    \
    v2f m0, m1;                                                              \
    RQ_CH3(q_w + 0,  SA, SB, SC,                                             \
           rqA[DY][0] = a0; rqA[DY][1] = a1; m0 = a0; m1 = a1;)              \
    RQ_CH3(q_w + 9,  SA, SB, SC,                                             \
           rqB[DY][0] = a0; rqB[DY][1] = a1; RQ_MX)                          \
    RQ_CH3(q_w + 18, SA, SB, SC, RQ_ST5(0) RQ_MX)                            \
    RQ_CH3(q_w + 27, SA, SB, SC, RQ_ST5(1) RQ_MX)                            \
    RQ_CH3(q_w + 36, SA, SB, SC, RQ_ST5(2) RQ_MX)                            \
    RQ_CH3(q_w + 45, SA, SB, SC, RQ_ST5(3) RQ_MX)                            \
    RQ_CH3(q_w + 54, SA, SB, SC, RQ_ST5(4) RQ_MX)                            \
    RQ_CH3(q_w + 63, SA, SB, SC, RQ_MX)                                      \
    RQ_CH3(q_w + 72, SA, SB, SC, RQ_MX)                                      \
    RQ_CH3(q_w + 81, SA, SB, SC, RQ_MX)                                      \
    float* v_ = vwr + (DY) * LCOLS;                                          \
    v_[1] = m0.x; v_[2] = m0.y; v_[3] = m1.x; v_[4] = m1.y;                  \
  }

// Register-rq channel (v-half only, 18 pk-fma).
#define VI_CHREG(RQ, WOFF, DY, SA, SB, SC, MERGE)                            \
    {                                                                        \
      const float* wc = w_in + (WOFF);                                       \
      v2f a0 = RQ[DY][0];                                                    \
      v2f a1 = RQ[DY][1];                                                    \
      TAP_V(SA, wc[0], wc[1], wc[2])                                         \
      TAP_V(SB, wc[3], wc[4], wc[5])                                         \
      TAP_V(SC, wc[6], wc[7], wc[8])                                         \
      MERGE                                                                  \
    }

// ws-loaded rq channel: b128 load (L3-resident) + v-half only.
#define VI_CHLD(C5, WOFF, SA, SB, SC, MERGE)                                 \
    {                                                                        \
      const float4 q_ = *reinterpret_cast<const float4*>(lr + (C5) * WSD);   \
      const float* wc = w_in + (WOFF);                                       \
      v2f a0 = (v2f){q_.x, q_.y};                                            \
      v2f a1 = (v2f){q_.z, q_.w};                                            \
      TAP_V(SA, wc[0], wc[1], wc[2])                                         \
      TAP_V(SB, wc[3], wc[4], wc[5])                                         \
      TAP_V(SC, wc[6], wc[7], wc[8])                                         \
      MERGE                                                                  \
    }

#define VI_MX15                                                              \
      o0 = __builtin_elementwise_max(o0, a0);                                \
      o1 = __builtin_elementwise_max(o1, a1);

// ---------- VI output row: 2 reg + 5 ws-loaded + 3 recompute channels -----
#define VI_OUT15(DY, SA, SB, SC)                                             \
  {                                                                          \
    const float* lr = rq5_t + (DY) * (5 * WSD);                              \
    v2f o0, o1;                                                              \
    VI_CHREG(rqA, 0,  DY, SA, SB, SC, o0 = a0; o1 = a1;)                     \
    VI_CHREG(rqB, 9,  DY, SA, SB, SC, VI_MX15)                               \
    VI_CHLD(0, 18, SA, SB, SC, VI_MX15)                                      \
    VI_CHLD(1, 27, SA, SB, SC, VI_MX15)                                      \
    VI_CHLD(2, 36, SA, SB, SC, VI_MX15)                                      \
    VI_CHLD(3, 45, SA, SB, SC, VI_MX15)                                      \
    VI_CHLD(4, 54, SA, SB, SC, VI_MX15)                                      \
    _Pragma("unroll 3")                                                      \
    for (int c = 7; c < LQ; ++c) {                                           \
      VI_CH3(q_w + c * 9, w_in + c * 9, SA, SB, SC, VI_MX15)                 \
    }                                                                        \
    float* w_ = wr + (DY) * LCOLS;                                           \
    w_[1] = o0.x; w_[2] = o0.y; w_[3] = o1.x; w_[4] = o1.y;                  \
  }

// ---------------- Primary kernel (round 15) ----------------
__global__ __launch_bounds__(1024)
__attribute__((amdgpu_waves_per_eu(4, 4)))
void vin_rg(const float* __restrict__ input,
            const int* __restrict__ coords,
            const float* __restrict__ q_w,
            const float* __restrict__ w_in,
            const float* __restrict__ fc_w,
            float* __restrict__ ws,
            float* __restrict__ out) {
  extern __shared__ float lds[];
  float* pA = lds;          // stages ch0; then r copy; then v ping-pong A
  float* pB = lds + PLANE;  // stages ch1; then v0 / v ping-pong B
  const float* w_eff = ws;  // 19 floats
  float* g_r = ws + WSOFF_RPLANES + (size_t)blockIdx.x * PLANE;

  const int b = blockIdx.x;
  const int tid = threadIdx.x;
  const int ty = tid >> 5;              // 0..31
  const int tx = tid & 31;              // 0..31
  const int y0 = ty << 2;               // output rows y0..y0+3
  const int x0 = tx << 2;               // output cols x0..x0+3
  const int nb_base = y0 * LCOLS + x0;  // window base
  const int wrow0 = (y0 + 1) * LCOLS + x0;  // write row base (dwords +1..+4)

  // per-thread rq5 base: [y][c5][x] layout, channels 2..6, interior only
  float* rq5_t = ws + WSOFF_RQ5 + (size_t)b * RQ5PLANE + (y0 * 5) * WSD + x0;

  // rq register tiles for channels 0/1 (live across the whole VI loop)
  v2f rqA[4][2], rqB[4][2];

  // zero LDS planes; zero only the HALO of the global r plane (interior is
  // fully overwritten by the r-phase before any read)
  for (int i = tid; i < LDS_DWORDS; i += 1024) lds[i] = 0.0f;
  if (tid < LCOLS) { g_r[tid] = 0.0f; g_r[129 * LCOLS + tid] = 0.0f; }
  if (tid >= 256 && tid < 384) {
    const int row = tid - 255;  // 1..128
    g_r[row * LCOLS + 0] = 0.0f;
    g_r[row * LCOLS + 129] = 0.0f;
    g_r[row * LCOLS + 130] = 0.0f;
    g_r[row * LCOLS + 131] = 0.0f;
  }
  __syncthreads();

  // stage input: ch0 -> pA interior, ch1 -> pB interior (+1 dword col shift)
  const float* in0 = input + (size_t)b * (LI * HS * WSD);
  const float* in1 = in0 + HS * WSD;
  {
    const float4* in40 = (const float4*)in0;
    const float4* in41 = (const float4*)in1;
    for (int i = tid; i < HS * WSD / 4; i += 1024) {
      const int y = i >> 5, x4 = (i & 31) << 2;
      const float4 a = in40[i];
      const float4 c = in41[i];
      float* r_ = pA + (y + 1) * LCOLS + x4;
      float* v_ = pB + (y + 1) * LCOLS + x4;
      r_[1] = a.x; r_[2] = a.y; r_[3] = a.z; r_[4] = a.w;
      v_[1] = c.x; v_[2] = c.y; v_[3] = c.z; v_[4] = c.w;
    }
  }
  __syncthreads();

  // ---- r = conv(input, W_eff, pad=1) + b_eff -> pA interior AND g_r ----
  {
    const float* rp = pA + nb_base;
    const float* vp = pB + nb_base;
    v2f rw[3][3], vw[3][3], racc[4][2];
    LOAD_PROW(rp, 0, rw[0]) LOAD_PROW(rp, 1, rw[1]) LOAD_PROW(rp, 2, rw[2])
    LOAD_PROW(vp, 0, vw[0]) LOAD_PROW(vp, 1, vw[1]) LOAD_PROW(vp, 2, vw[2])
    const float beff = w_eff[18];
    R_ROW(0) WIN_SHIFT2(3) R_ROW(1) WIN_SHIFT2(4) R_ROW(2) WIN_SHIFT2(5) R_ROW(3)
    __syncthreads();  // all staged-input reads (pA and pB) done
#pragma unroll
    for (int dy = 0; dy < 4; ++dy) {
      float* g_ = g_r + wrow0 + dy * LCOLS;
      float* r_ = pA + wrow0 + dy * LCOLS;
      g_[1] = racc[dy][0].x; g_[2] = racc[dy][0].y;
      g_[3] = racc[dy][1].x; g_[4] = racc[dy][1].y;
      r_[1] = racc[dy][0].x; r_[2] = racc[dy][0].y;
      r_[3] = racc[dy][1].x; r_[4] = racc[dy][1].y;
    }
  }
  __syncthreads();  // r plane visible in pA (and draining to g_r)

  // ---- rq-phase: ch0/1 -> regs; ch2..6 -> ws; v0 = max_c rq -> pB ----
  {
    const float* rp = pA + nb_base;
    float* vwr = pB + wrow0;
    v2f rP[3][3];
    LOADR(0, 0) LOADR(1, 1) LOADR(2, 2)
    RQ_OUT15(0, 0, 1, 2)
    LOADR(0, 3)
    RQ_OUT15(1, 1, 2, 0)
    LOADR(1, 4)
    RQ_OUT15(2, 2, 0, 1)
    LOADR(2, 5)
    RQ_OUT15(3, 0, 1, 2)
  }
  __syncthreads();  // v0 visible; g_r + rq5 stores drained (barrier waits vmcnt)

  // ---- 39 VI iterations (v0 already = iteration 1 of the old loop) ----
  // it even: read pB, write pA; it odd: read pA, write pB -> final v in pA.
  const float* grp = g_r + nb_base;
#pragma unroll 1
  for (int it = 0; it < KIT - 1; ++it) {
    const float* vp = lds + ((it & 1) ? 0 : PLANE) + nb_base;
    float* wr = lds + ((it & 1) ? PLANE : 0) + wrow0;
    const float* rp = grp;  // global, L2-resident, iteration-invariant
    v2f rP[3][3], vE[3][3], vO[3][2];
    LOADR(0, 0) LOADR(1, 1) LOADR(2, 2)
    LOADV(0, 0) LOADV(1, 1) LOADV(2, 2)
    VI_OUT15(0, 0, 1, 2)
    LOADR(0, 3) LOADV(0, 3)
    VI_OUT15(1, 1, 2, 0)
    LOADR(1, 4) LOADV(1, 4)
    VI_OUT15(2, 2, 0, 1)
    LOADR(2, 5) LOADV(2, 5)
    VI_OUT15(3, 0, 1, 2)
    __syncthreads();  // write-plane visible; next iter swaps planes
  }

  // ---- epilogue: q at (sx,sy) from g_r + final v (pA); logits. ----
  if (tid == 0) {
    const int sx = coords[b * 4 + 0];
    const int sy = coords[b * 4 + 1];
    float qv[LQ];
#pragma unroll 1
    for (int c = 0; c < LQ; ++c) {
      float s = 0.0f;
#pragma unroll
      for (int kk = 0; kk < 9; ++kk) {
        const int ky = kk / 3, kx = kk % 3;
        const int off = (sx + ky) * LCOLS + (sy + kx);
        s = __builtin_fmaf(q_w[c * 9 + kk], g_r[off],
            __builtin_fmaf(w_in[c * 9 + kk], pA[off], s));
      }
      qv[c] = s;
    }
#pragma unroll 1
    for (int a = 0; a < AOUT; ++a) {
      float s = 0.0f;
#pragma unroll
      for (int c = 0; c < LQ; ++c)
        s = __builtin_fmaf(fc_w[a * LQ + c], qv[c], s);
      out[b * AOUT + a] = s;
    }
  }
}

// ---------------- Fallback (round-8 structure): all-LDS, no workspace.
#define VI_CH(QC, WC, MERGE)                                                 \
  {                                                                          \
    const float* qc = (QC);                                                  \
    const float* wc = (WC);                                                  \
    v2f a0 = SPLAT(qc[0]) * rw[0][0];                                        \
    v2f a1 = SPLAT(qc[0]) * rw[0][1];                                        \
    a0.x = __builtin_fmaf(qc[1], rw[0][0].y, a0.x);                          \
    a0.y = __builtin_fmaf(qc[1], rw[0][1].x, a0.y);                          \
    a1.x = __builtin_fmaf(qc[1], rw[0][1].y, a1.x);                          \
    a1.y = __builtin_fmaf(qc[1], rw[0][2].x, a1.y);                          \
    a0 = FMA2(SPLAT(qc[2]), rw[0][1], a0);                                   \
    a1 = FMA2(SPLAT(qc[2]), rw[0][2], a1);                                   \
    TAPROW(1, rw, qc[3], qc[4], qc[5])                                       \
    TAPROW(2, rw, qc[6], qc[7], qc[8])                                       \
    TAPROW(0, vw, wc[0], wc[1], wc[2])                                       \
    TAPROW(1, vw, wc[3], wc[4], wc[5])                                       \
    TAPROW(2, vw, wc[6], wc[7], wc[8])                                       \
    MERGE                                                                    \
  }

#define VI_ROW_L(DY)                                                         \
  {                                                                          \
    v2f o0, o1;                                                              \
    VI_CH(q_w, w_in, o0 = a0; o1 = a1;)                                      \
    _Pragma("unroll 3")                                                      \
    for (int c = 1; c < LQ; ++c) {                                           \
      VI_CH(q_w + c * 9, w_in + c * 9,                                       \
            o0 = __builtin_elementwise_max(o0, a0);                          \
            o1 = __builtin_elementwise_max(o1, a1);)                         \
    }                                                                        \
    outv[DY][0] = o0; outv[DY][1] = o1;                                      \
  }

__global__ __launch_bounds__(1024)
__attribute__((amdgpu_waves_per_eu(4, 4)))
void vin_lds(const float* __restrict__ input,
             const int* __restrict__ coords,
             const float* __restrict__ q_w,
             const float* __restrict__ w_in,
             const float* __restrict__ fc_w,
             const float* __restrict__ w_eff,
             float* __restrict__ out) {
  extern __shared__ float lds[];
  float* rplane = lds;
  float* vplane = lds + PLANE;

  const int b = blockIdx.x;
  const int tid = threadIdx.x;
  const int ty = tid >> 5;
  const int tx = tid & 31;
  const int y0 = ty << 2;
  const int x0 = tx << 2;
  const int nb_base = y0 * LCOLS + x0;
  const int wrow0 = (y0 + 1) * LCOLS + x0;

  for (int i = tid; i < LDS_DWORDS; i += 1024) lds[i] = 0.0f;
  __syncthreads();

  const float* in0 = input + (size_t)b * (LI * HS * WSD);
  const float* in1 = in0 + HS * WSD;
  {
    const float4* in40 = (const float4*)in0;
    const float4* in41 = (const float4*)in1;
    for (int i = tid; i < HS * WSD / 4; i += 1024) {
      const int y = i >> 5, x4 = (i & 31) << 2;
      const float4 a = in40[i];
      const float4 c = in41[i];
      float* r_ = rplane + (y + 1) * LCOLS + x4;
      float* v_ = vplane + (y + 1) * LCOLS + x4;
      r_[1] = a.x; r_[2] = a.y; r_[3] = a.z; r_[4] = a.w;
      v_[1] = c.x; v_[2] = c.y; v_[3] = c.z; v_[4] = c.w;
    }
  }
  __syncthreads();

  {
    const float* rp = rplane + nb_base;
    const float* vp = vplane + nb_base;
    v2f rw[3][3], vw[3][3], racc[4][2];
    LOAD_PROW(rp, 0, rw[0]) LOAD_PROW(rp, 1, rw[1]) LOAD_PROW(rp, 2, rw[2])
    LOAD_PROW(vp, 0, vw[0]) LOAD_PROW(vp, 1, vw[1]) LOAD_PROW(vp, 2, vw[2])
    const float beff = w_eff[18];
    R_ROW(0) WIN_SHIFT2(3) R_ROW(1) WIN_SHIFT2(4) R_ROW(2) WIN_SHIFT2(5) R_ROW(3)
    __syncthreads();
#pragma unroll
    for (int dy = 0; dy < 4; ++dy) {
      float* r_ = rplane + wrow0 + dy * LCOLS;
      float* v_ = vplane + wrow0 + dy * LCOLS;
      r_[1] = racc[dy][0].x; r_[2] = racc[dy][0].y;
      r_[3] = racc[dy][1].x; r_[4] = racc[dy][1].y;
      v_[1] = 0.0f; v_[2] = 0.0f; v_[3] = 0.0f; v_[4] = 0.0f;
    }
  }
  __syncthreads();

#pragma unroll 1
  for (int it = 0; it < KIT; ++it) {
    const float* rp = rplane + nb_base;
    const float* vp = vplane + nb_base;
    v2f rw[3][3], vw[3][3], outv[4][2];
    LOAD_PROW(rp, 0, rw[0]) LOAD_PROW(rp, 1, rw[1]) LOAD_PROW(rp, 2, rw[2])
    LOAD_PROW(vp, 0, vw[0]) LOAD_PROW(vp, 1, vw[1]) LOAD_PROW(vp, 2, vw[2])
    VI_ROW_L(0) WIN_SHIFT2(3) VI_ROW_L(1) WIN_SHIFT2(4) VI_ROW_L(2) WIN_SHIFT2(5) VI_ROW_L(3)
    __syncthreads();
#pragma unroll
    for (int dy = 0; dy < 4; ++dy) {
      float* v_ = vplane + wrow0 + dy * LCOLS;
      v_[1] = outv[dy][0].x; v_[2] = outv[dy][0].y;
      v_[3] = outv[dy][1].x; v_[4] = outv[dy][1].y;
    }
    __syncthreads();
  }

  if (tid == 0) {
    const int sx = coords[b * 4 + 0];
    const int sy = coords[b * 4 + 1];
    float qv[LQ];
#pragma unroll 1
    for (int c = 0; c < LQ; ++c) {
      float s = 0.0f;
#pragma unroll
      for (int kk = 0; kk < 9; ++kk) {
        const int ky = kk / 3, kx = kk % 3;
        const int off = (sx + ky) * LCOLS + (sy + kx);
        s = __builtin_fmaf(q_w[c * 9 + kk], rplane[off],
            __builtin_fmaf(w_in[c * 9 + kk], vplane[off], s));
      }
      qv[c] = s;
    }
#pragma unroll 1
    for (int a = 0; a < AOUT; ++a) {
      float s = 0.0f;
#pragma unroll
      for (int c = 0; c < LQ; ++c)
        s = __builtin_fmaf(fc_w[a * LQ + c], qv[c], s);
      out[b * AOUT + a] = s;
    }
  }
}

extern "C" void kernel_launch(void* const* d_in, const int* in_sizes, int n_in,
                              void* d_out, int out_size, void* d_ws, size_t ws_size,
                              hipStream_t stream) {
  const float* input = (const float*)d_in[0];   // (B, 2, 128, 128)
  const int*   coords = (const int*)d_in[1];    // (B, 4)
  const float* h_w = (const float*)d_in[2];     // (150, 2, 3, 3)
  const float* h_b = (const float*)d_in[3];     // (150,)
  const float* r_w = (const float*)d_in[4];     // (1, 150, 1, 1)
  const float* q_w = (const float*)d_in[5];     // (10, 1, 3, 3)
  const float* w_in = (const float*)d_in[6];    // (10, 1, 3, 3)
  const float* fc_w = (const float*)d_in[7];    // (5, 10)
  float* out = (float*)d_out;                   // (B, 5)
  float* ws = (float*)d_ws;

  const size_t smem = (size_t)LDS_DWORDS * sizeof(float);  // 137,280 B

  prep_weff<<<1, 64, 0, stream>>>(h_w, h_b, r_w, ws);

  if (ws_size >= WS_NEED15) {
    hipFuncSetAttribute(reinterpret_cast<const void*>(vin_rg),
                        hipFuncAttributeMaxDynamicSharedMemorySize, (int)smem);
    vin_rg<<<NBATCH, 1024, smem, stream>>>(input, coords, q_w, w_in, fc_w, ws, out);
  } else {
    hipFuncSetAttribute(reinterpret_cast<const void*>(vin_lds),
                        hipFuncAttributeMaxDynamicSharedMemorySize, (int)smem);
    vin_lds<<<NBATCH, 1024, smem, stream>>>(input, coords, q_w, w_in, fc_w, ws, out);
  }
}

// Round 8
// 618.795 us; speedup vs baseline: 1.4098x; 1.4098x over previous
//
#include <hip/hip_runtime.h>

// Problem constants (from reference)
#define NBATCH 256
#define LI 2
#define LH 150
#define LQ 10
#define HS 128
#define WSD 128
#define KIT 40
#define AOUT 5

// Plane layout: 130 rows x 132 cols of dwords, pixel (y,x) -> plane[(y+1)*LCOLS + (x+1)].
// Row 0 / row 129 = zero halos; dword col 0 = left halo; cols 129..131 = right
// zero pad. With x0 = 4*tx, a thread's 6-wide window = dwords x0..x0+5:
// b128@x0 (16B aligned) + b64@x0+4; b128 halves are the even pairs.
#define LCOLS 132
#define LROWS 130
#define PLANE (LROWS * LCOLS)      // 17160 dwords
#define LDS_DWORDS (2 * PLANE)     // 137,280 B

// Workspace (floats): [0..18] w_eff | [64..) per-block r planes (PLANE each)
#define WSOFF_RPLANES 64
#define WS_NEED_BYTES ((size_t)(WSOFF_RPLANES + NBATCH * PLANE) * 4)

typedef float v2f __attribute__((ext_vector_type(2)));
#define SPLAT(K) ((v2f){(K), (K)})
#define FMA2(A, B, C) __builtin_elementwise_fma((A), (B), (C))

// ---- Prep: collapse the linear hidden layer.
__global__ void prep_weff(const float* __restrict__ h_w,
                          const float* __restrict__ h_b,
                          const float* __restrict__ r_w,
                          float* __restrict__ w_eff) {
  const int t = threadIdx.x;
  if (t < 18) {
    const int i = t / 9, k = t % 9;
    double s = 0.0;
    for (int h = 0; h < LH; ++h)
      s += (double)r_w[h] * (double)h_w[(h * LI + i) * 9 + k];
    w_eff[t] = (float)s;
  } else if (t == 18) {
    double s = 0.0;
    for (int h = 0; h < LH; ++h)
      s += (double)r_w[h] * (double)h_b[h];
    w_eff[18] = (float)s;
  }
}

// SROA RULE (rounds 1-4): local arrays only ever indexed by compile-time
// literals. VALU LAW: f32-issue-bound; only issue-count cuts move the needle.
// VGPR WALL LAW (r13/r14): 64 VGPRs is a hard budget; attributes don't move
// it; >64 live => scratch spill (FETCH blows up).
// MEMORY TIER LAW (r9/r10/r15): reuse cache = per-XCD L2 (4 MB). g_r
// (2.2 MB/XCD) is L2-resident; any added iteration-read set > ~2 MB/XCD
// misses to HBM (L3 retains ~20% only). No tier left for rq beyond 2
// register channels.
// ROUND 12 (base, 600 us, VGPR 60): rq-phase + ch0/ch1 register-rq, 39 iters.
// ROUND 16: single variable on r12 — pk-ify kx=1 r-taps via odd pairs rO
// (built once per slot-load; bitwise-identical fma order). 8 recompute
// channels 44->38 issues. r11 bundled this with poison; isolated here.

// ---------- shared macros ----------
#define LOAD_PROW(P, R, W)                                                   \
  {                                                                          \
    const float4 b_ = *reinterpret_cast<const float4*>((P) + (R) * LCOLS);   \
    const float2 c_ = *reinterpret_cast<const float2*>((P) + (R) * LCOLS + 4); \
    W[0] = (v2f){b_.x, b_.y};                                                \
    W[1] = (v2f){b_.z, b_.w};                                                \
    W[2] = (v2f){c_.x, c_.y};                                                \
  }

#define TAPROW(KY, WARR, K0, K1, K2)                                         \
    a0 = FMA2(SPLAT(K0), WARR[KY][0], a0);                                   \
    a1 = FMA2(SPLAT(K0), WARR[KY][1], a1);                                   \
    a0.x = __builtin_fmaf((K1), WARR[KY][0].y, a0.x);                        \
    a0.y = __builtin_fmaf((K1), WARR[KY][1].x, a0.y);                        \
    a1.x = __builtin_fmaf((K1), WARR[KY][1].y, a1.x);                        \
    a1.y = __builtin_fmaf((K1), WARR[KY][2].x, a1.y);                        \
    a0 = FMA2(SPLAT(K2), WARR[KY][1], a0);                                   \
    a1 = FMA2(SPLAT(K2), WARR[KY][2], a1);

#define WIN_SHIFT2(NEXTROW)                                                  \
  {                                                                          \
    _Pragma("unroll")                                                        \
    for (int j = 0; j < 3; ++j) {                                            \
      rw[0][j] = rw[1][j]; rw[1][j] = rw[2][j];                              \
      vw[0][j] = vw[1][j]; vw[1][j] = vw[2][j];                              \
    }                                                                        \
    LOAD_PROW(rp, (NEXTROW), rw[2])                                          \
    LOAD_PROW(vp, (NEXTROW), vw[2])                                          \
  }

#define R_ROW(DY)                                                            \
  {                                                                          \
    v2f a0 = SPLAT(beff);                                                    \
    v2f a1 = a0;                                                             \
    TAPROW(0, rw, w_eff[0], w_eff[1], w_eff[2])                              \
    TAPROW(1, rw, w_eff[3], w_eff[4], w_eff[5])                              \
    TAPROW(2, rw, w_eff[6], w_eff[7], w_eff[8])                              \
    TAPROW(0, vw, w_eff[9], w_eff[10], w_eff[11])                            \
    TAPROW(1, vw, w_eff[12], w_eff[13], w_eff[14])                           \
    TAPROW(2, vw, w_eff[15], w_eff[16], w_eff[17])                           \
    racc[DY][0] = a0; racc[DY][1] = a1;                                      \
  }

// ---------- mod-3 slot machinery ----------
// r window slot, even pairs only (rq-phase: scalar kx=1 taps).
#define LOADR(SLOT, R)                                                       \
  {                                                                          \
    const float4 b_ = *reinterpret_cast<const float4*>(rp + (R) * LCOLS);    \
    const float2 c_ = *reinterpret_cast<const float2*>(rp + (R) * LCOLS + 4); \
    rP[SLOT][0] = (v2f){b_.x, b_.y};                                         \
    rP[SLOT][1] = (v2f){b_.z, b_.w};                                         \
    rP[SLOT][2] = (v2f){c_.x, c_.y};                                         \
  }

// r window slot, even + odd pairs (VI loop: all-pk r taps).
#define LOADR2(SLOT, R)                                                      \
  {                                                                          \
    const float4 b_ = *reinterpret_cast<const float4*>(rp + (R) * LCOLS);    \
    const float2 c_ = *reinterpret_cast<const float2*>(rp + (R) * LCOLS + 4); \
    rP[SLOT][0] = (v2f){b_.x, b_.y};                                         \
    rP[SLOT][1] = (v2f){b_.z, b_.w};                                         \
    rP[SLOT][2] = (v2f){c_.x, c_.y};                                         \
    rO[SLOT][0] = (v2f){b_.y, b_.z};                                         \
    rO[SLOT][1] = (v2f){b_.w, c_.x};                                         \
  }

// v window slot: even pairs + odd pairs (built once, reused x10 chans).
#define LOADV(SLOT, R)                                                       \
  {                                                                          \
    const float4 b_ = *reinterpret_cast<const float4*>(vp + (R) * LCOLS);    \
    const float2 c_ = *reinterpret_cast<const float2*>(vp + (R) * LCOLS + 4); \
    vE[SLOT][0] = (v2f){b_.x, b_.y};                                         \
    vE[SLOT][1] = (v2f){b_.z, b_.w};                                         \
    vE[SLOT][2] = (v2f){c_.x, c_.y};                                         \
    vO[SLOT][0] = (v2f){b_.y, b_.z};                                         \
    vO[SLOT][1] = (v2f){b_.w, c_.x};                                         \
  }

// r tap-row, scalar kx=1: 8 issues (rq-phase only).
#define TAP_R(SLOT, K0, K1, K2)                                              \
    a0 = FMA2(SPLAT(K0), rP[SLOT][0], a0);                                   \
    a1 = FMA2(SPLAT(K0), rP[SLOT][1], a1);                                   \
    a0.x = __builtin_fmaf((K1), rP[SLOT][0].y, a0.x);                        \
    a0.y = __builtin_fmaf((K1), rP[SLOT][1].x, a0.y);                        \
    a1.x = __builtin_fmaf((K1), rP[SLOT][1].y, a1.x);                        \
    a1.y = __builtin_fmaf((K1), rP[SLOT][2].x, a1.y);                        \
    a0 = FMA2(SPLAT(K2), rP[SLOT][1], a0);                                   \
    a1 = FMA2(SPLAT(K2), rP[SLOT][2], a1);

// r tap-row, all-pk via rO: 6 issues. pk lane x == scalar a0.x fma etc.,
// same K0->K1->K2 order -> bitwise identical to TAP_R.
#define TAP_R2(SLOT, K0, K1, K2)                                             \
    a0 = FMA2(SPLAT(K0), rP[SLOT][0], a0);                                   \
    a1 = FMA2(SPLAT(K0), rP[SLOT][1], a1);                                   \
    a0 = FMA2(SPLAT(K1), rO[SLOT][0], a0);                                   \
    a1 = FMA2(SPLAT(K1), rO[SLOT][1], a1);                                   \
    a0 = FMA2(SPLAT(K2), rP[SLOT][1], a0);                                   \
    a1 = FMA2(SPLAT(K2), rP[SLOT][2], a1);

// v tap-row: all-pk, 6 issues.
#define TAP_V(SLOT, K0, K1, K2)                                              \
    a0 = FMA2(SPLAT(K0), vE[SLOT][0], a0);                                   \
    a1 = FMA2(SPLAT(K0), vE[SLOT][1], a1);                                   \
    a0 = FMA2(SPLAT(K1), vO[SLOT][0], a0);                                   \
    a1 = FMA2(SPLAT(K1), vO[SLOT][1], a1);                                   \
    a0 = FMA2(SPLAT(K2), vE[SLOT][1], a0);                                   \
    a1 = FMA2(SPLAT(K2), vE[SLOT][2], a1);

// Full channel, all-pk r taps (VI loop): 36 + merge = 38 issues.
#define VI_CH3P(QC, WC, SA, SB, SC, MERGE)                                   \
  {                                                                          \
    const float* qc = (QC);                                                  \
    const float* wc = (WC);                                                  \
    v2f a0 = SPLAT(qc[0]) * rP[SA][0];                                       \
    v2f a1 = SPLAT(qc[0]) * rP[SA][1];                                       \
    a0 = FMA2(SPLAT(qc[1]), rO[SA][0], a0);                                  \
    a1 = FMA2(SPLAT(qc[1]), rO[SA][1], a1);                                  \
    a0 = FMA2(SPLAT(qc[2]), rP[SA][1], a0);                                  \
    a1 = FMA2(SPLAT(qc[2]), rP[SA][2], a1);                                  \
    TAP_R2(SB, qc[3], qc[4], qc[5])                                          \
    TAP_R2(SC, qc[6], qc[7], qc[8])                                          \
    TAP_V(SA, wc[0], wc[1], wc[2])                                           \
    TAP_V(SB, wc[3], wc[4], wc[5])                                           \
    TAP_V(SC, wc[6], wc[7], wc[8])                                           \
    MERGE                                                                    \
  }

// ---------- one-time rq-phase machinery (r12 form, unchanged) ----------
#define RQ_CH3(QC, SA, SB, SC, MERGE)                                        \
  {                                                                          \
    const float* qc = (QC);                                                  \
    v2f a0 = SPLAT(qc[0]) * rP[SA][0];                                       \
    v2f a1 = SPLAT(qc[0]) * rP[SA][1];                                       \
    a0.x = __builtin_fmaf(qc[1], rP[SA][0].y, a0.x);                         \
    a0.y = __builtin_fmaf(qc[1], rP[SA][1].x, a0.y);                         \
    a1.x = __builtin_fmaf(qc[1], rP[SA][1].y, a1.x);                         \
    a1.y = __builtin_fmaf(qc[1], rP[SA][2].x, a1.y);                         \
    a0 = FMA2(SPLAT(qc[2]), rP[SA][1], a0);                                  \
    a1 = FMA2(SPLAT(qc[2]), rP[SA][2], a1);                                  \
    TAP_R(SB, qc[3], qc[4], qc[5])                                           \
    TAP_R(SC, qc[6], qc[7], qc[8])                                           \
    MERGE                                                                    \
  }

#define RQ_MX                                                                \
    m0 = __builtin_elementwise_max(m0, a0);                                  \
    m1 = __builtin_elementwise_max(m1, a1);

// One rq output row: ch0/ch1 -> registers; all 10 -> running max -> v0 row.
#define RQ_OUT11(DY, SA, SB, SC)                                             \
  {                                                                          \
    v2f m0, m1;                                                              \
    RQ_CH3(q_w + 0,  SA, SB, SC,                                             \
           rqA[DY][0] = a0; rqA[DY][1] = a1; m0 = a0; m1 = a1;)              \
    RQ_CH3(q_w + 9,  SA, SB, SC,                                             \
           rqB[DY][0] = a0; rqB[DY][1] = a1; RQ_MX)                          \
    RQ_CH3(q_w + 18, SA, SB, SC, RQ_MX)                                      \
    RQ_CH3(q_w + 27, SA, SB, SC, RQ_MX)                                      \
    RQ_CH3(q_w + 36, SA, SB, SC, RQ_MX)                                      \
    RQ_CH3(q_w + 45, SA, SB, SC, RQ_MX)                                      \
    RQ_CH3(q_w + 54, SA, SB, SC, RQ_MX)                                      \
    RQ_CH3(q_w + 63, SA, SB, SC, RQ_MX)                                      \
    RQ_CH3(q_w + 72, SA, SB, SC, RQ_MX)                                      \
    RQ_CH3(q_w + 81, SA, SB, SC, RQ_MX)                                      \
    float* v_ = vwr + (DY) * LCOLS;                                          \
    v_[1] = m0.x; v_[2] = m0.y; v_[3] = m1.x; v_[4] = m1.y;                  \
  }

// ---------- VI output row: 2 register channels + 8 pk-recompute channels ----
#define VI_OUT16(DY, SA, SB, SC)                                             \
  {                                                                          \
    v2f o0, o1;                                                              \
    {                                                                        \
      const float* wc = w_in;                                                \
      v2f a0 = rqA[DY][0];                                                   \
      v2f a1 = rqA[DY][1];                                                   \
      TAP_V(SA, wc[0], wc[1], wc[2])                                         \
      TAP_V(SB, wc[3], wc[4], wc[5])                                         \
      TAP_V(SC, wc[6], wc[7], wc[8])                                         \
      o0 = a0; o1 = a1;                                                      \
    }                                                                        \
    {                                                                        \
      const float* wc = w_in + 9;                                            \
      v2f a0 = rqB[DY][0];                                                   \
      v2f a1 = rqB[DY][1];                                                   \
      TAP_V(SA, wc[0], wc[1], wc[2])                                         \
      TAP_V(SB, wc[3], wc[4], wc[5])                                         \
      TAP_V(SC, wc[6], wc[7], wc[8])                                         \
      o0 = __builtin_elementwise_max(o0, a0);                                \
      o1 = __builtin_elementwise_max(o1, a1);                                \
    }                                                                        \
    _Pragma("unroll 3")                                                      \
    for (int c = 2; c < LQ; ++c) {                                           \
      VI_CH3P(q_w + c * 9, w_in + c * 9, SA, SB, SC,                         \
              o0 = __builtin_elementwise_max(o0, a0);                        \
              o1 = __builtin_elementwise_max(o1, a1);)                       \
    }                                                                        \
    float* w_ = wr + (DY) * LCOLS;                                           \
    w_[1] = o0.x; w_[2] = o0.y; w_[3] = o1.x; w_[4] = o1.y;                  \
  }

// ---------------- Primary kernel (round 16) ----------------
__global__ __launch_bounds__(1024)
__attribute__((amdgpu_waves_per_eu(4, 4)))
void vin_rg(const float* __restrict__ input,
            const int* __restrict__ coords,
            const float* __restrict__ q_w,
            const float* __restrict__ w_in,
            const float* __restrict__ fc_w,
            float* __restrict__ ws,
            float* __restrict__ out) {
  extern __shared__ float lds[];
  float* pA = lds;          // stages ch0; then r copy; then v ping-pong A
  float* pB = lds + PLANE;  // stages ch1; then v0 / v ping-pong B
  const float* w_eff = ws;  // 19 floats
  float* g_r = ws + WSOFF_RPLANES + (size_t)blockIdx.x * PLANE;

  const int b = blockIdx.x;
  const int tid = threadIdx.x;
  const int ty = tid >> 5;              // 0..31
  const int tx = tid & 31;              // 0..31
  const int y0 = ty << 2;               // output rows y0..y0+3
  const int x0 = tx << 2;               // output cols x0..x0+3
  const int nb_base = y0 * LCOLS + x0;  // window base
  const int wrow0 = (y0 + 1) * LCOLS + x0;  // write row base (dwords +1..+4)

  // rq register tiles for channels 0 and 1 (live across the whole VI loop)
  v2f rqA[4][2], rqB[4][2];

  // zero LDS planes; zero only the HALO of the global r plane (interior is
  // fully overwritten by the r-phase before any read)
  for (int i = tid; i < LDS_DWORDS; i += 1024) lds[i] = 0.0f;
  if (tid < LCOLS) { g_r[tid] = 0.0f; g_r[129 * LCOLS + tid] = 0.0f; }
  if (tid >= 256 && tid < 384) {
    const int row = tid - 255;  // 1..128
    g_r[row * LCOLS + 0] = 0.0f;
    g_r[row * LCOLS + 129] = 0.0f;
    g_r[row * LCOLS + 130] = 0.0f;
    g_r[row * LCOLS + 131] = 0.0f;
  }
  __syncthreads();

  // stage input: ch0 -> pA interior, ch1 -> pB interior (+1 dword col shift)
  const float* in0 = input + (size_t)b * (LI * HS * WSD);
  const float* in1 = in0 + HS * WSD;
  {
    const float4* in40 = (const float4*)in0;
    const float4* in41 = (const float4*)in1;
    for (int i = tid; i < HS * WSD / 4; i += 1024) {
      const int y = i >> 5, x4 = (i & 31) << 2;
      const float4 a = in40[i];
      const float4 c = in41[i];
      float* r_ = pA + (y + 1) * LCOLS + x4;
      float* v_ = pB + (y + 1) * LCOLS + x4;
      r_[1] = a.x; r_[2] = a.y; r_[3] = a.z; r_[4] = a.w;
      v_[1] = c.x; v_[2] = c.y; v_[3] = c.z; v_[4] = c.w;
    }
  }
  __syncthreads();

  // ---- r = conv(input, W_eff, pad=1) + b_eff -> pA interior AND g_r ----
  {
    const float* rp = pA + nb_base;
    const float* vp = pB + nb_base;
    v2f rw[3][3], vw[3][3], racc[4][2];
    LOAD_PROW(rp, 0, rw[0]) LOAD_PROW(rp, 1, rw[1]) LOAD_PROW(rp, 2, rw[2])
    LOAD_PROW(vp, 0, vw[0]) LOAD_PROW(vp, 1, vw[1]) LOAD_PROW(vp, 2, vw[2])
    const float beff = w_eff[18];
    R_ROW(0) WIN_SHIFT2(3) R_ROW(1) WIN_SHIFT2(4) R_ROW(2) WIN_SHIFT2(5) R_ROW(3)
    __syncthreads();  // all staged-input reads (pA and pB) done
#pragma unroll
    for (int dy = 0; dy < 4; ++dy) {
      float* g_ = g_r + wrow0 + dy * LCOLS;
      float* r_ = pA + wrow0 + dy * LCOLS;
      g_[1] = racc[dy][0].x; g_[2] = racc[dy][0].y;
      g_[3] = racc[dy][1].x; g_[4] = racc[dy][1].y;
      r_[1] = racc[dy][0].x; r_[2] = racc[dy][0].y;
      r_[3] = racc[dy][1].x; r_[4] = racc[dy][1].y;
    }
  }
  __syncthreads();  // r plane visible in pA (and draining to g_r)

  // ---- rq-phase: ch0/ch1 rq -> registers; v0 = max_c rq -> pB ----
  {
    const float* rp = pA + nb_base;
    float* vwr = pB + wrow0;
    v2f rP[3][3];
    LOADR(0, 0) LOADR(1, 1) LOADR(2, 2)
    RQ_OUT11(0, 0, 1, 2)
    LOADR(0, 3)
    RQ_OUT11(1, 1, 2, 0)
    LOADR(1, 4)
    RQ_OUT11(2, 2, 0, 1)
    LOADR(2, 5)
    RQ_OUT11(3, 0, 1, 2)
  }
  __syncthreads();  // v0 visible; g_r stores drained (barrier waits vmcnt)

  // ---- 39 VI iterations (v0 already = iteration 1 of the old loop) ----
  // it even: read pB, write pA; it odd: read pA, write pB -> final v in pA.
  const float* grp = g_r + nb_base;
#pragma unroll 1
  for (int it = 0; it < KIT - 1; ++it) {
    const float* vp = lds + ((it & 1) ? 0 : PLANE) + nb_base;
    float* wr = lds + ((it & 1) ? PLANE : 0) + wrow0;
    const float* rp = grp;  // global, L2-resident, iteration-invariant
    v2f rP[3][3], rO[3][2], vE[3][3], vO[3][2];
    LOADR2(0, 0) LOADR2(1, 1) LOADR2(2, 2)
    LOADV(0, 0) LOADV(1, 1) LOADV(2, 2)
    VI_OUT16(0, 0, 1, 2)
    LOADR2(0, 3) LOADV(0, 3)
    VI_OUT16(1, 1, 2, 0)
    LOADR2(1, 4) LOADV(1, 4)
    VI_OUT16(2, 2, 0, 1)
    LOADR2(2, 5) LOADV(2, 5)
    VI_OUT16(3, 0, 1, 2)
    __syncthreads();  // write-plane visible; next iter swaps planes
  }

  // ---- epilogue: q at (sx,sy) from g_r + final v (pA); logits. ----
  if (tid == 0) {
    const int sx = coords[b * 4 + 0];
    const int sy = coords[b * 4 + 1];
    float qv[LQ];
#pragma unroll 1
    for (int c = 0; c < LQ; ++c) {
      float s = 0.0f;
#pragma unroll
      for (int kk = 0; kk < 9; ++kk) {
        const int ky = kk / 3, kx = kk % 3;
        const int off = (sx + ky) * LCOLS + (sy + kx);
        s = __builtin_fmaf(q_w[c * 9 + kk], g_r[off],
            __builtin_fmaf(w_in[c * 9 + kk], pA[off], s));
      }
      qv[c] = s;
    }
#pragma unroll 1
    for (int a = 0; a < AOUT; ++a) {
      float s = 0.0f;
#pragma unroll
      for (int c = 0; c < LQ; ++c)
        s = __builtin_fmaf(fc_w[a * LQ + c], qv[c], s);
      out[b * AOUT + a] = s;
    }
  }
}

// ---------------- Fallback (round-8 structure): all-LDS, no r workspace.
#define VI_CH(QC, WC, MERGE)                                                 \
  {                                                                          \
    const float* qc = (QC);                                                  \
    const float* wc = (WC);                                                  \
    v2f a0 = SPLAT(qc[0]) * rw[0][0];                                        \
    v2f a1 = SPLAT(qc[0]) * rw[0][1];                                        \
    a0.x = __builtin_fmaf(qc[1], rw[0][0].y, a0.x);                          \
    a0.y = __builtin_fmaf(qc[1], rw[0][1].x, a0.y);                          \
    a1.x = __builtin_fmaf(qc[1], rw[0][1].y, a1.x);                          \
    a1.y = __builtin_fmaf(qc[1], rw[0][2].x, a1.y);                          \
    a0 = FMA2(SPLAT(qc[2]), rw[0][1], a0);                                   \
    a1 = FMA2(SPLAT(qc[2]), rw[0][2], a1);                                   \
    TAPROW(1, rw, qc[3], qc[4], qc[5])                                       \
    TAPROW(2, rw, qc[6], qc[7], qc[8])                                       \
    TAPROW(0, vw, wc[0], wc[1], wc[2])                                       \
    TAPROW(1, vw, wc[3], wc[4], wc[5])                                       \
    TAPROW(2, vw, wc[6], wc[7], wc[8])                                       \
    MERGE                                                                    \
  }

#define VI_ROW_L(DY)                                                         \
  {                                                                          \
    v2f o0, o1;                                                              \
    VI_CH(q_w, w_in, o0 = a0; o1 = a1;)                                      \
    _Pragma("unroll 3")                                                      \
    for (int c = 1; c < LQ; ++c) {                                           \
      VI_CH(q_w + c * 9, w_in + c * 9,                                       \
            o0 = __builtin_elementwise_max(o0, a0);                          \
            o1 = __builtin_elementwise_max(o1, a1);)                         \
    }                                                                        \
    outv[DY][0] = o0; outv[DY][1] = o1;                                      \
  }

__global__ __launch_bounds__(1024)
__attribute__((amdgpu_waves_per_eu(4, 4)))
void vin_lds(const float* __restrict__ input,
             const int* __restrict__ coords,
             const float* __restrict__ q_w,
             const float* __restrict__ w_in,
             const float* __restrict__ fc_w,
             const float* __restrict__ w_eff,
             float* __restrict__ out) {
  extern __shared__ float lds[];
  float* rplane = lds;
  float* vplane = lds + PLANE;

  const int b = blockIdx.x;
  const int tid = threadIdx.x;
  const int ty = tid >> 5;
  const int tx = tid & 31;
  const int y0 = ty << 2;
  const int x0 = tx << 2;
  const int nb_base = y0 * LCOLS + x0;
  const int wrow0 = (y0 + 1) * LCOLS + x0;

  for (int i = tid; i < LDS_DWORDS; i += 1024) lds[i] = 0.0f;
  __syncthreads();

  const float* in0 = input + (size_t)b * (LI * HS * WSD);
  const float* in1 = in0 + HS * WSD;
  {
    const float4* in40 = (const float4*)in0;
    const float4* in41 = (const float4*)in1;
    for (int i = tid; i < HS * WSD / 4; i += 1024) {
      const int y = i >> 5, x4 = (i & 31) << 2;
      const float4 a = in40[i];
      const float4 c = in41[i];
      float* r_ = rplane + (y + 1) * LCOLS + x4;
      float* v_ = vplane + (y + 1) * LCOLS + x4;
      r_[1] = a.x; r_[2] = a.y; r_[3] = a.z; r_[4] = a.w;
      v_[1] = c.x; v_[2] = c.y; v_[3] = c.z; v_[4] = c.w;
    }
  }
  __syncthreads();

  {
    const float* rp = rplane + nb_base;
    const float* vp = vplane + nb_base;
    v2f rw[3][3], vw[3][3], racc[4][2];
    LOAD_PROW(rp, 0, rw[0]) LOAD_PROW(rp, 1, rw[1]) LOAD_PROW(rp, 2, rw[2])
    LOAD_PROW(vp, 0, vw[0]) LOAD_PROW(vp, 1, vw[1]) LOAD_PROW(vp, 2, vw[2])
    const float beff = w_eff[18];
    R_ROW(0) WIN_SHIFT2(3) R_ROW(1) WIN_SHIFT2(4) R_ROW(2) WIN_SHIFT2(5) R_ROW(3)
    __syncthreads();
#pragma unroll
    for (int dy = 0; dy < 4; ++dy) {
      float* r_ = rplane + wrow0 + dy * LCOLS;
      float* v_ = vplane + wrow0 + dy * LCOLS;
      r_[1] = racc[dy][0].x; r_[2] = racc[dy][0].y;
      r_[3] = racc[dy][1].x; r_[4] = racc[dy][1].y;
      v_[1] = 0.0f; v_[2] = 0.0f; v_[3] = 0.0f; v_[4] = 0.0f;
    }
  }
  __syncthreads();

#pragma unroll 1
  for (int it = 0; it < KIT; ++it) {
    const float* rp = rplane + nb_base;
    const float* vp = vplane + nb_base;
    v2f rw[3][3], vw[3][3], outv[4][2];
    LOAD_PROW(rp, 0, rw[0]) LOAD_PROW(rp, 1, rw[1]) LOAD_PROW(rp, 2, rw[2])
    LOAD_PROW(vp, 0, vw[0]) LOAD_PROW(vp, 1, vw[1]) LOAD_PROW(vp, 2, vw[2])
    VI_ROW_L(0) WIN_SHIFT2(3) VI_ROW_L(1) WIN_SHIFT2(4) VI_ROW_L(2) WIN_SHIFT2(5) VI_ROW_L(3)
    __syncthreads();
#pragma unroll
    for (int dy = 0; dy < 4; ++dy) {
      float* v_ = vplane + wrow0 + dy * LCOLS;
      v_[1] = outv[dy][0].x; v_[2] = outv[dy][0].y;
      v_[3] = outv[dy][1].x; v_[4] = outv[dy][1].y;
    }
    __syncthreads();
  }

  if (tid == 0) {
    const int sx = coords[b * 4 + 0];
    const int sy = coords[b * 4 + 1];
    float qv[LQ];
#pragma unroll 1
    for (int c = 0; c < LQ; ++c) {
      float s = 0.0f;
#pragma unroll
      for (int kk = 0; kk < 9; ++kk) {
        const int ky = kk / 3, kx = kk % 3;
        const int off = (sx + ky) * LCOLS + (sy + kx);
        s = __builtin_fmaf(q_w[c * 9 + kk], rplane[off],
            __builtin_fmaf(w_in[c * 9 + kk], vplane[off], s));
      }
      qv[c] = s;
    }
#pragma unroll 1
    for (int a = 0; a < AOUT; ++a) {
      float s = 0.0f;
#pragma unroll
      for (int c = 0; c < LQ; ++c)
        s = __builtin_fmaf(fc_w[a * LQ + c], qv[c], s);
      out[b * AOUT + a] = s;
    }
  }
}

extern "C" void kernel_launch(void* const* d_in, const int* in_sizes, int n_in,
                              void* d_out, int out_size, void* d_ws, size_t ws_size,
                              hipStream_t stream) {
  const float* input = (const float*)d_in[0];   // (B, 2, 128, 128)
  const int*   coords = (const int*)d_in[1];    // (B, 4)
  const float* h_w = (const float*)d_in[2];     // (150, 2, 3, 3)
  const float* h_b = (const float*)d_in[3];     // (150,)
  const float* r_w = (const float*)d_in[4];     // (1, 150, 1, 1)
  const float* q_w = (const float*)d_in[5];     // (10, 1, 3, 3)
  const float* w_in = (const float*)d_in[6];    // (10, 1, 3, 3)
  const float* fc_w = (const float*)d_in[7];    // (5, 10)
  float* out = (float*)d_out;                   // (B, 5)
  float* ws = (float*)d_ws;

  const size_t smem = (size_t)LDS_DWORDS * sizeof(float);  // 137,280 B

  prep_weff<<<1, 64, 0, stream>>>(h_w, h_b, r_w, ws);

  if (ws_size >= WS_NEED_BYTES) {
    hipFuncSetAttribute(reinterpret_cast<const void*>(vin_rg),
                        hipFuncAttributeMaxDynamicSharedMemorySize, (int)smem);
    vin_rg<<<NBATCH, 1024, smem, stream>>>(input, coords, q_w, w_in, fc_w, ws, out);
  } else {
    hipFuncSetAttribute(reinterpret_cast<const void*>(vin_lds),
                        hipFuncAttributeMaxDynamicSharedMemorySize, (int)smem);
    vin_lds<<<NBATCH, 1024, smem, stream>>>(input, coords, q_w, w_in, fc_w, ws, out);
  }
}